// Round 12
// baseline (474.500 us; speedup 1.0000x reference)
//
#include <hip/hip_runtime.h>
#include <hip/hip_bf16.h>

#define BATCH 32
#define SEQ   2048
#define HID   1024
#define M_TOT (BATCH*SEQ)
#define NG    32          // K groups of 32 (passes: xh*wh, xh*wl, xl*wh)

typedef __attribute__((ext_vector_type(8)))  short          bf16x8;
typedef __attribute__((ext_vector_type(8)))  unsigned short us8;
typedef __attribute__((ext_vector_type(16))) float          f32x16;

__device__ __forceinline__ unsigned short f2bf_rn(float x) {
    unsigned u = __float_as_uint(x);
    return (unsigned short)((u + 0x7fffu + ((u >> 16) & 1u)) >> 16);
}
__device__ __forceinline__ float bf2f(unsigned short h) {
    return __uint_as_float(((unsigned)h) << 16);
}
// packed f32x2 -> bf16x2 (lo <- s0, hi <- s1), RTNE on gfx950
__device__ __forceinline__ unsigned cvt_pk_bf16(float s0, float s1) {
    unsigned r;
    asm("v_cvt_pk_bf16_f32 %0, %1, %2" : "=v"(r) : "v"(s0), "v"(s1));
    return r;
}

using as1_cv = const __attribute__((address_space(1))) void;
using as3_v  = __attribute__((address_space(3))) void;
__device__ __forceinline__ void gload16(const void* g, char* s) {
    __builtin_amdgcn_global_load_lds((as1_cv*)g, (as3_v*)s, 16, 0, 0);
}

#define FENCE() asm volatile("" ::: "memory")
#define BAR_P()  do { FENCE(); __builtin_amdgcn_s_barrier(); FENCE(); } while (0)
#define BAR_LG() do { asm volatile("s_waitcnt lgkmcnt(0)" ::: "memory"); \
                      __builtin_amdgcn_s_barrier(); FENCE(); } while (0)
#define BAR_VM8() do { asm volatile("s_waitcnt vmcnt(8) lgkmcnt(0)" ::: "memory"); \
                       __builtin_amdgcn_s_barrier(); FENCE(); } while (0)

// 8 MFMAs: i-pair x 2 j x 2 k-halves, 32x32x16 each
#define MB32(Af, Bf, IB) do { \
  _Pragma("unroll") for (int i_ = 0; i_ < 2; i_++) \
  _Pragma("unroll") for (int j_ = 0; j_ < 2; j_++) { \
    acc[(IB)+i_][j_] = __builtin_amdgcn_mfma_f32_32x32x16_bf16(Af[i_][0], Bf[j_][0], acc[(IB)+i_][j_], 0, 0, 0); \
    acc[(IB)+i_][j_] = __builtin_amdgcn_mfma_f32_32x32x16_bf16(Af[i_][1], Bf[j_][1], acc[(IB)+i_][j_], 0, 0, 0); \
  } \
} while (0)

// ---------------- kernel 0: W f32 -> bf16 hi/lo  w2 = [o][ wh(1024) | wl(1024) ] --
__global__ __launch_bounds__(256) void k_convW(const float* __restrict__ W,
                                               unsigned short* __restrict__ w2) {
    const int i8 = (blockIdx.x * 256 + threadIdx.x) * 8;
    const int o = i8 >> 10, h = i8 & 1023;
    float4 w0 = *(const float4*)(W + i8);
    float4 w1 = *(const float4*)(W + i8 + 4);
    float xs[8] = {w0.x, w0.y, w0.z, w0.w, w1.x, w1.y, w1.z, w1.w};
    us8 hv{}, lv{};
#pragma unroll
    for (int t = 0; t < 8; t++) {
        unsigned short xh = f2bf_rn(xs[t]);
        hv[t] = (unsigned short)xh;
        lv[t] = (unsigned short)f2bf_rn(xs[t] - bf2f(xh));
    }
    *(us8*)(w2 + (size_t)o * 2048 + h)        = hv;
    *(us8*)(w2 + (size_t)o * 2048 + 1024 + h) = lv;
}

// ------- kernel 0b: cb[b][n] = hidden[b] . W[n] + b_attn[n]  (fp32 exact) ----
__global__ __launch_bounds__(256) void k_hw(const float* __restrict__ W,
                                            const float* __restrict__ hidden,
                                            const float* __restrict__ b_attn,
                                            float* __restrict__ cb) {
    __shared__ float hid[HID];
    const int t = threadIdx.x, b = blockIdx.y;
#pragma unroll
    for (int i = 0; i < 4; i++)
        hid[t + i * 256] = hidden[(size_t)b * HID + t + i * 256];
    __syncthreads();
    const int n = blockIdx.x * 256 + t;
    const float* wr = W + (size_t)n * HID;
    float a = 0.f;
#pragma unroll 4
    for (int k = 0; k < HID; k += 4) {
        float4 w4 = *(const float4*)(wr + k);
        a += w4.x * hid[k] + w4.y * hid[k + 1] + w4.z * hid[k + 2] + w4.w * hid[k + 3];
    }
    cb[(size_t)b * HID + n] = a + b_attn[n];
}

// ------ kernel 1: fused enc @ W^T (+cb) -> tanh -> dot(v) -> pscore16 ------
// ROUND-4 SKELETON (phases/barriers identical to the 392us champion), with:
//  * MFMA 32x32x16 (m119: 2495 vs 2176 TF; half the instruction count)
//  * rank-1: conv is pure enc hi/lo split; cb = hidden.W + b added in epilogue
// LDS (128 KB, XOR-swizzled: 16B-chunk c of row r at c ^ ((r>>1)&3)):
//   A 2 slots x [xh|xl] x [256][64B] @0; B 2 slots x [wh|wl] x [256][64B] @65536.
// Frag (32x32x16): lane l reads row (blk*32 + (l&31)), k-half (l>>5) -> 16B.
__global__ __launch_bounds__(512, 2) void k_gemm_scores(
    const float* __restrict__ enc,
    const unsigned short* __restrict__ w2,
    const float* __restrict__ cb,
    const float* __restrict__ v,
    float* __restrict__ pscore16)
{
    extern __shared__ char smem[];

    const int tid  = threadIdx.x;
    const int lane = tid & 63, wid = tid >> 6;
    const int wr = wid >> 2, wc = wid & 3;          // 2 x 4 wave grid
    const int r31 = lane & 31, hl = lane >> 5;
    const int sw31 = (r31 >> 1) & 3;                // lane-constant row swizzle

    const int bid  = blockIdx.x;
    const int swz  = (bid & 7) * 128 + (bid >> 3);  // XCD-chunk swizzle (bijective)
    const int mbase = (swz >> 2) * 256;
    const int nbase = (swz & 3) * 256;
    const int bidx  = mbase >> 11;                  // batch (BM=256 divides SEQ)

    // A conversion mapping: thread -> (row, 16-col half)
    const int arow = tid >> 1;
    const int acol = (tid & 1) * 16;
    const int axr  = (arow >> 1) & 3;
    const int ao0  = (((tid & 1) * 2) ^ axr) * 16;
    const int ao1  = ao0 ^ 16;
    const float* encP = enc + (size_t)(mbase + arow) * HID + acol;

    // B gload mapping: dest linear (lane*16); source chunk pre-swizzled
    const int brow  = wid * 16 + (lane >> 2);
    const int bsx8  = ((lane & 3) ^ ((lane >> 3) & 3)) * 8;

    f32x16 acc[4][2];
#pragma unroll
    for (int i = 0; i < 4; i++)
#pragma unroll
        for (int j = 0; j < 2; j++) acc[i][j] = (f32x16)0.f;

    float4 er[4];

    auto loadEnc = [&](int Gn) {
        const float* ep = encP + Gn * 32;
#pragma unroll
        for (int q = 0; q < 4; q++) er[q] = *(const float4*)(ep + q * 4);
    };
    // pure enc hi/lo split (rank-1: hidden handled via cb), cvt_pk packed
    auto convA = [&](int Gn) {
        char* ap = smem + (Gn & 1) * 32768 + arow * 64;
        unsigned hpk[8], lpk[8];
#pragma unroll
        for (int q = 0; q < 4; q++) {
            float4 e = er[q];
            unsigned p01 = cvt_pk_bf16(e.x, e.y);
            unsigned p23 = cvt_pk_bf16(e.z, e.w);
            float h0 = __uint_as_float(p01 << 16);
            float h1 = __uint_as_float(p01 & 0xffff0000u);
            float h2 = __uint_as_float(p23 << 16);
            float h3 = __uint_as_float(p23 & 0xffff0000u);
            hpk[q * 2]     = p01;
            hpk[q * 2 + 1] = p23;
            lpk[q * 2]     = cvt_pk_bf16(e.x - h0, e.y - h1);
            lpk[q * 2 + 1] = cvt_pk_bf16(e.z - h2, e.w - h3);
        }
        *(uint4*)(ap + ao0)          = make_uint4(hpk[0], hpk[1], hpk[2], hpk[3]);
        *(uint4*)(ap + ao1)          = make_uint4(hpk[4], hpk[5], hpk[6], hpk[7]);
        *(uint4*)(ap + 16384 + ao0)  = make_uint4(lpk[0], lpk[1], lpk[2], lpk[3]);
        *(uint4*)(ap + 16384 + ao1)  = make_uint4(lpk[4], lpk[5], lpk[6], lpk[7]);
    };
    auto stageB = [&](int G2, int part) {   // part: 0=wh, 1=wl ; 2 gloads
        const unsigned short* s0 = w2 + (size_t)(nbase + brow) * 2048 + part * 1024 + G2 * 32 + bsx8;
        char* d0 = smem + 65536 + (G2 & 1) * 32768 + part * 16384 + wid * 1024;
        gload16(s0, d0);
        gload16(s0 + (size_t)128 * 2048, d0 + 8192);
    };
    // 32x32x16 fragment reads: row blk*32 + r31, k-half h*2+hl (16B), swizzled
    auto rdA = [&](int slot, int part, int i, int h) -> bf16x8 {
        return *(const bf16x8*)(smem + slot * 32768 + part * 16384 +
                                (wr * 128 + i * 32 + r31) * 64 +
                                ((h * 2 + hl) ^ sw31) * 16);
    };
    auto rdB = [&](int slot, int part, int j, int h) -> bf16x8 {
        return *(const bf16x8*)(smem + 65536 + slot * 32768 + part * 16384 +
                                (wc * 64 + j * 32 + r31) * 64 +
                                ((h * 2 + hl) ^ sw31) * 16);
    };

    // ---- prologue (r4 pattern, hidL-free) ----
    stageB(0, 0); stageB(0, 1);
    loadEnc(0);
    stageB(1, 0); stageB(1, 1);
    convA(0);                 // er(0) reg-dep wait transitively drains B(0) DMAs
    loadEnc(1);

    bf16x8 aa[2][2], aa2[2][2], bh[2][2], bl[2][2];

    for (int G = 0; G < NG; ++G) {
        const int slot = G & 1;
        const int Gs = (G + 2 < NG) ? G + 2 : G;      // tail: restage same bytes
        const int Ge = (G + 2 < NG) ? G + 2 : NG - 1; // tail: clamp (er unused)
        // ---- top: A(G)/B(G) ready; 8 outstanding VMEM = no stall ----
        BAR_VM8();
        // ---------- ph1: read xh(i0,1) + wh + wl; MFMA xh01*wh ----------
#pragma unroll
        for (int ii = 0; ii < 2; ii++)
#pragma unroll
            for (int h = 0; h < 2; h++) aa[ii][h] = rdA(slot, 0, ii, h);
#pragma unroll
        for (int j = 0; j < 2; j++)
#pragma unroll
            for (int h = 0; h < 2; h++) bh[j][h] = rdB(slot, 0, j, h);
#pragma unroll
        for (int j = 0; j < 2; j++)
#pragma unroll
            for (int h = 0; h < 2; h++) bl[j][h] = rdB(slot, 1, j, h);
        __builtin_amdgcn_s_setprio(1);
        MB32(aa, bh, 0);
        __builtin_amdgcn_s_setprio(0);
        // ph1-end: drain (ph2's DMA re-targets wh bytes ph1 read)
        BAR_LG();
        // ---------- ph2: stage wh(G+2); MFMA xh01*wl ----------
        stageB(Gs, 0);
        __builtin_amdgcn_s_setprio(1);
        MB32(aa, bl, 0);
        __builtin_amdgcn_s_setprio(0);
        BAR_P();
        // ---------- ph3: read xh(i2,3); stage wl(G+2); MFMA xh23*wh ----------
#pragma unroll
        for (int ii = 0; ii < 2; ii++)
#pragma unroll
            for (int h = 0; h < 2; h++) aa2[ii][h] = rdA(slot, 0, 2 + ii, h);
        stageB(Gs, 1);
        __builtin_amdgcn_s_setprio(1);
        MB32(aa2, bh, 2);
        __builtin_amdgcn_s_setprio(0);
        BAR_P();
        // ---------- ph4: convA(G+1) -> slot^1; enc(G+2); MFMA xh23*wl ----------
        if (G + 1 < NG) convA(G + 1);
        loadEnc(Ge);
        __builtin_amdgcn_s_setprio(1);
        MB32(aa2, bl, 2);
        __builtin_amdgcn_s_setprio(0);
        BAR_P();
        // ---------- ph5: read xl(i0,1); MFMA xl01*wh ----------
#pragma unroll
        for (int ii = 0; ii < 2; ii++)
#pragma unroll
            for (int h = 0; h < 2; h++) aa[ii][h] = rdA(slot, 1, ii, h);
        __builtin_amdgcn_s_setprio(1);
        MB32(aa, bh, 0);
        __builtin_amdgcn_s_setprio(0);
        // ---------- ph6: read xl(i2,3); MFMA xl23*wh (no barrier) ----------
#pragma unroll
        for (int ii = 0; ii < 2; ii++)
#pragma unroll
            for (int h = 0; h < 2; h++) aa2[ii][h] = rdA(slot, 1, 2 + ii, h);
        __builtin_amdgcn_s_setprio(1);
        MB32(aa2, bh, 2);
        __builtin_amdgcn_s_setprio(0);
    }

    // ---- epilogue: tanh(e+cb)*v, reduce over cols (32x32 C layout) ----
    // C: col = lane&31, row = (reg&3) + 8*(reg>>2) + 4*hl  (+ i*32 + wr*128)
    float rs[4][16];
#pragma unroll
    for (int i = 0; i < 4; i++)
#pragma unroll
        for (int t = 0; t < 16; t++) rs[i][t] = 0.f;

#pragma unroll
    for (int j = 0; j < 2; j++) {
        const int n = nbase + wc * 64 + j * 32 + r31;
        const float ba = cb[(size_t)bidx * HID + n];
        const float vv = v[n];
#pragma unroll
        for (int i = 0; i < 4; i++)
#pragma unroll
            for (int t = 0; t < 16; t++) {
                float e  = acc[i][j][t] + ba;
                float ex = __expf(2.f * e);
                rs[i][t] += (1.f - 2.f / (ex + 1.f)) * vv;
            }
    }
    // butterfly over the 32 cols within each lane-half
#pragma unroll
    for (int off = 1; off < 32; off <<= 1)
#pragma unroll
        for (int i = 0; i < 4; i++)
#pragma unroll
            for (int t = 0; t < 16; t++) rs[i][t] += __shfl_xor(rs[i][t], off, 64);

    // lane slot r31 selects (i0 = r31>>4, reg = r31&15); writes 2 rows
    float v0 = 0.f, v1 = 0.f;
#pragma unroll
    for (int i = 0; i < 2; i++)
#pragma unroll
        for (int t = 0; t < 16; t++)
            if (r31 == i * 16 + t) { v0 = rs[i][t]; v1 = rs[i + 2][t]; }

    const int reg  = r31 & 15;
    const int i0   = r31 >> 4;
    const int rloc = i0 * 32 + (reg & 3) + 8 * (reg >> 2) + 4 * hl;
    const int plane = (swz & 3) * 4 + wc;
    const size_t pb = (size_t)plane * M_TOT + mbase + wr * 128;
    pscore16[pb + rloc]      = v0;
    pscore16[pb + rloc + 64] = v1;
}

// ---------------- kernel 2: sum 16 partial planes + softmax over S ----------
__global__ __launch_bounds__(256) void k_softmax(const float* __restrict__ ps,
                                                 float* __restrict__ out) {
    const int b = blockIdx.x, t = threadIdx.x;
    __shared__ float red[8];
    float loc[8];
    float lmax = -1e30f;
#pragma unroll
    for (int i = 0; i < 8; i++) {
        const int s = t + i * 256;
        float sc = 0.f;
#pragma unroll
        for (int p = 0; p < 16; p++) sc += ps[(size_t)p * M_TOT + (size_t)b * SEQ + s];
        loc[i] = sc;
        lmax = fmaxf(lmax, sc);
    }
    for (int o = 32; o; o >>= 1) lmax = fmaxf(lmax, __shfl_xor(lmax, o, 64));
    if ((t & 63) == 0) red[t >> 6] = lmax;
    __syncthreads();
    const float bmax = fmaxf(fmaxf(red[0], red[1]), fmaxf(red[2], red[3]));
    float ev[8], lsum = 0.f;
#pragma unroll
    for (int i = 0; i < 8; i++) { ev[i] = expf(loc[i] - bmax); lsum += ev[i]; }
    for (int o = 32; o; o >>= 1) lsum += __shfl_xor(lsum, o, 64);
    __syncthreads();
    if ((t & 63) == 0) red[4 + (t >> 6)] = lsum;
    __syncthreads();
    const float inv = 1.f / (red[4] + red[5] + red[6] + red[7]);
#pragma unroll
    for (int i = 0; i < 8; i++)
        out[(size_t)BATCH * HID + (size_t)b * SEQ + t + i * 256] = ev[i] * inv;
}

// ---------------- kernel 3: partial context over S-chunks -------------------
__global__ __launch_bounds__(256) void k_pctx(const float* __restrict__ enc,
                                              const float* __restrict__ attn,
                                              float* __restrict__ pctx) {
    const int hc = blockIdx.x, scb = blockIdx.y, b = blockIdx.z;
    const int h = hc * 256 + threadIdx.x;
    const float* ap = attn + (size_t)b * SEQ + scb * 256;
    const float* ep = enc + ((size_t)b * SEQ + scb * 256) * HID + h;
    float a = 0.f;
#pragma unroll 4
    for (int s = 0; s < 256; s++) a += ap[s] * ep[(size_t)s * HID];
    pctx[((size_t)scb * BATCH + b) * HID + h] = a;
}

// ---------------- kernel 4: reduce partial contexts -------------------------
__global__ __launch_bounds__(256) void k_ctx(const float* __restrict__ pctx,
                                             float* __restrict__ out) {
    const int i = blockIdx.x * 256 + threadIdx.x;
    float a = 0.f;
#pragma unroll
    for (int p = 0; p < 8; p++) a += pctx[(size_t)p * BATCH * HID + i];
    out[i] = a;
}

extern "C" void kernel_launch(void* const* d_in, const int* in_sizes, int n_in,
                              void* d_out, int out_size, void* d_ws, size_t ws_size,
                              hipStream_t stream) {
    const float* hidden = (const float*)d_in[0];
    const float* enc    = (const float*)d_in[1];
    const float* W      = (const float*)d_in[2];
    const float* b_attn = (const float*)d_in[3];
    const float* v      = (const float*)d_in[4];
    float* out = (float*)d_out;

    char* ws = (char*)d_ws;
    unsigned short* w2 = (unsigned short*)ws;                 // 4 MB (dead after gemm)
    float* pscore16    = (float*)(ws + ((size_t)4 << 20));    // 4 MB
    float* cb          = (float*)(ws + ((size_t)8 << 20));    // 128 KB
    float* pctx        = (float*)ws;                          // reuses w2 post-gemm

    const int smemBytes = 131072;
    hipFuncSetAttribute((const void*)k_gemm_scores,
                        hipFuncAttributeMaxDynamicSharedMemorySize, smemBytes);

    k_convW<<<dim3(512), dim3(256), 0, stream>>>(W, w2);
    k_hw<<<dim3(4, 32), dim3(256), 0, stream>>>(W, hidden, b_attn, cb);
    k_gemm_scores<<<dim3(1024), dim3(512), smemBytes, stream>>>(
        enc, w2, cb, v, pscore16);
    k_softmax<<<dim3(BATCH), dim3(256), 0, stream>>>(pscore16, out);
    k_pctx<<<dim3(4, 8, BATCH), dim3(256), 0, stream>>>(enc, out + BATCH * HID, pctx);
    k_ctx<<<dim3(128), dim3(256), 0, stream>>>(pctx, out);
}